// Round 1
// baseline (205.151 us; speedup 1.0000x reference)
//
#include <hip/hip_runtime.h>
#include <math.h>

#define KK 5
#define HDIM 64
#define C_DIM 256
#define LIN 4096
#define B_DIM 4
#define N_PTS 8192
#define IN_DIM 258   // C + x + cell
#define OUT_DIM 12   // 1 + 1 + K + K

__device__ __forceinline__ float leaky(float v) {
    return v >= 0.0f ? v : 0.2f * v;
}
__device__ __forceinline__ float softplus_f(float v) {
    return v > 20.0f ? v : log1pf(expf(v));
}

// ---------------- Kernel 1: transpose feat [B][C][L] -> feat_t [B][L][C] ----
__global__ __launch_bounds__(256) void transpose_kernel(
    const float* __restrict__ feat, float* __restrict__ feat_t)
{
    __shared__ float tile[32][33];
    int b  = blockIdx.z;
    int l0 = blockIdx.x * 32;
    int c0 = blockIdx.y * 32;
    const float* src = feat + (size_t)b * C_DIM * LIN;
    float* dst       = feat_t + (size_t)b * LIN * C_DIM;
    int tx = threadIdx.x, ty = threadIdx.y;   // (32, 8)
#pragma unroll
    for (int i = 0; i < 4; i++) {
        tile[ty + i * 8][tx] = src[(size_t)(c0 + ty + i * 8) * LIN + (l0 + tx)];
    }
    __syncthreads();
#pragma unroll
    for (int i = 0; i < 4; i++) {
        dst[(size_t)(l0 + ty + i * 8) * C_DIM + (c0 + tx)] = tile[tx][ty + i * 8];
    }
}

// ---------------- Kernel 2: per-point MLP -> params (5 ix + 5 norm weights) -
// Block = 256 threads, 64 points/block in 4 chunks of 16.
__global__ __launch_bounds__(256) void mlp_kernel(
    const float* __restrict__ feat_t,
    const float* __restrict__ coords,
    const float* __restrict__ cell,
    const float* __restrict__ W1, const float* __restrict__ b1,
    const float* __restrict__ Wr, const float* __restrict__ br,
    const float* __restrict__ W3, const float* __restrict__ b3,
    float* __restrict__ params)
{
    __shared__ float W1s[IN_DIM * 64];    // 66048 B
    __shared__ float Wrs[64 * 64];        // 16384 B
    __shared__ float W3s[64 * 12];        //  3072 B
    __shared__ float b1s[64], brs[64], b3s[12];
    __shared__ float anch[16][260];       // 16640 B (256 feat + x + cell, pad->260)
    __shared__ float h1s[16][65];
    __shared__ float h2s[16][65];
    __shared__ float outs[16][12];
    __shared__ int   i0s[16], i1s[16];
    __shared__ float fracs[16];

    const int t  = threadIdx.x;
    const int tx = t & 63;
    const int ty = t >> 6;

    // Stage weights once per block
    for (int idx = t; idx < IN_DIM * 64; idx += 256) W1s[idx] = W1[idx];
    for (int idx = t; idx < 64 * 64; idx += 256)     Wrs[idx] = Wr[idx];
    for (int idx = t; idx < 64 * 12; idx += 256)     W3s[idx] = W3[idx];
    if (t < 64) { b1s[t] = b1[t]; brs[t] = br[t]; }
    if (t < 12) { b3s[t] = b3[t]; }

    const int blockPt = blockIdx.x * 64;
    const int bb = blockPt >> 13;          // 64 | 8192, so one b per block
    const float* fb = feat_t + (size_t)bb * LIN * C_DIM;

    for (int chunk = 0; chunk < 4; chunk++) {
        const int base = blockPt + chunk * 16;
        __syncthreads();   // covers weight staging (chunk 0) + anch reuse

        // --- per-point bilinear setup (16 threads) ---
        if (t < 16) {
            int pt = base + t;
            float x  = coords[pt];
            float cl = cell[pt];
            float ix = (x + 1.0f) * 0.5f * (float)(LIN - 1);
            ix = fminf(fmaxf(ix, 0.0f), (float)(LIN - 1));
            float x0 = floorf(ix);
            int i0 = (int)x0;
            i0 = max(0, min(i0, LIN - 1));
            int i1 = min(i0 + 1, LIN - 1);
            i0s[t] = i0; i1s[t] = i1; fracs[t] = ix - x0;
            anch[t][256] = x; anch[t][257] = cl;
        }
        __syncthreads();

        // --- gather anchors: 16 threads/point, 16 channels each ---
        {
            int p = t >> 4;
            int cb = (t & 15) * 16;
            const float* r0 = fb + (size_t)i0s[p] * C_DIM;
            const float* r1 = fb + (size_t)i1s[p] * C_DIM;
            float fr = fracs[p];
#pragma unroll
            for (int q = 0; q < 4; q++) {
                int c = cb + q * 4;
                float4 f0 = *(const float4*)(r0 + c);
                float4 f1 = *(const float4*)(r1 + c);
                float4 a;
                a.x = f0.x * (1.0f - fr) + f1.x * fr;
                a.y = f0.y * (1.0f - fr) + f1.y * fr;
                a.z = f0.z * (1.0f - fr) + f1.z * fr;
                a.w = f0.w * (1.0f - fr) + f1.w * fr;
                *(float4*)&anch[p][c] = a;
            }
        }
        __syncthreads();

        // --- layer 1: j = tx, 4 points per thread ---
        {
            int p0 = ty * 4;
            float acc0 = b1s[tx], acc1 = acc0, acc2 = acc0, acc3 = acc0;
            for (int c = 0; c < 256; c += 4) {
                float4 a0 = *(const float4*)&anch[p0 + 0][c];
                float4 a1 = *(const float4*)&anch[p0 + 1][c];
                float4 a2 = *(const float4*)&anch[p0 + 2][c];
                float4 a3 = *(const float4*)&anch[p0 + 3][c];
                float w0 = W1s[(c + 0) * 64 + tx];
                float w1 = W1s[(c + 1) * 64 + tx];
                float w2 = W1s[(c + 2) * 64 + tx];
                float w3 = W1s[(c + 3) * 64 + tx];
                acc0 = fmaf(a0.x, w0, acc0); acc0 = fmaf(a0.y, w1, acc0);
                acc0 = fmaf(a0.z, w2, acc0); acc0 = fmaf(a0.w, w3, acc0);
                acc1 = fmaf(a1.x, w0, acc1); acc1 = fmaf(a1.y, w1, acc1);
                acc1 = fmaf(a1.z, w2, acc1); acc1 = fmaf(a1.w, w3, acc1);
                acc2 = fmaf(a2.x, w0, acc2); acc2 = fmaf(a2.y, w1, acc2);
                acc2 = fmaf(a2.z, w2, acc2); acc2 = fmaf(a2.w, w3, acc2);
                acc3 = fmaf(a3.x, w0, acc3); acc3 = fmaf(a3.y, w1, acc3);
                acc3 = fmaf(a3.z, w2, acc3); acc3 = fmaf(a3.w, w3, acc3);
            }
#pragma unroll
            for (int c = 256; c < 258; c++) {
                float wv = W1s[c * 64 + tx];
                acc0 = fmaf(anch[p0 + 0][c], wv, acc0);
                acc1 = fmaf(anch[p0 + 1][c], wv, acc1);
                acc2 = fmaf(anch[p0 + 2][c], wv, acc2);
                acc3 = fmaf(anch[p0 + 3][c], wv, acc3);
            }
            h1s[p0 + 0][tx] = leaky(acc0);
            h1s[p0 + 1][tx] = leaky(acc1);
            h1s[p0 + 2][tx] = leaky(acc2);
            h1s[p0 + 3][tx] = leaky(acc3);
        }
        __syncthreads();

        // --- layer 2 (residual) ---
        {
            int p0 = ty * 4;
            float acc0 = brs[tx], acc1 = acc0, acc2 = acc0, acc3 = acc0;
            for (int l = 0; l < 64; l++) {
                float wv = Wrs[l * 64 + tx];
                acc0 = fmaf(h1s[p0 + 0][l], wv, acc0);
                acc1 = fmaf(h1s[p0 + 1][l], wv, acc1);
                acc2 = fmaf(h1s[p0 + 2][l], wv, acc2);
                acc3 = fmaf(h1s[p0 + 3][l], wv, acc3);
            }
            h2s[p0 + 0][tx] = leaky(h1s[p0 + 0][tx] + acc0);
            h2s[p0 + 1][tx] = leaky(h1s[p0 + 1][tx] + acc1);
            h2s[p0 + 2][tx] = leaky(h1s[p0 + 2][tx] + acc2);
            h2s[p0 + 3][tx] = leaky(h1s[p0 + 3][tx] + acc3);
        }
        __syncthreads();

        // --- layer 3: p = t&15, o = t>>4 (12 outputs) ---
        if ((t >> 4) < 12) {
            int p = t & 15, o = t >> 4;
            float acc = b3s[o];
            for (int l = 0; l < 64; l++)
                acc = fmaf(h2s[p][l], W3s[l * 12 + o], acc);
            outs[p][o] = acc;
        }
        __syncthreads();

        // --- params: offsets + normalized weights (16 threads) ---
        if (t < 16) {
            int pt = base + t;
            float x = anch[t][256];
            float r  = softplus_f(outs[t][0]) + 0.3f;
            r = fminf(fmaxf(r, 0.3f), 2.0f);
            float sg = softplus_f(outs[t][1]) + 0.5f;
            sg = fminf(fmaxf(sg, 0.5f), 3.0f);
            float denom = (sg * 2.0f) * (sg * 2.0f) + 1e-8f;
            const float BASEv[KK] = {-2.0f, -1.0f, 0.0f, 1.0f, 2.0f};
            float ixk[KK], wk[KK];
            float wsum = 0.0f;
#pragma unroll
            for (int k = 0; k < KK; k++) {
                float res = tanhf(outs[t][2 + k]) * 0.5f;
                float off = r * BASEv[k] + res;
                float dx = x + off * (2.0f / (float)(LIN - 1));
                float ix = (dx + 1.0f) * 0.5f * (float)(LIN - 1);
                ix = fminf(fmaxf(ix, 0.0f), (float)(LIN - 1));
                float gate = outs[t][2 + KK + k];
                float wgeo = expf(-0.5f * off * off / denom);
                float sig  = 1.0f / (1.0f + expf(-gate));
                float w = wgeo * sig;
                ixk[k] = ix; wk[k] = w; wsum += w;
            }
            float inv = 1.0f / (wsum + 1e-8f);
            float* pp = params + (size_t)pt * 10;
#pragma unroll
            for (int k = 0; k < KK; k++) {
                pp[k]      = ixk[k];
                pp[5 + k]  = wk[k] * inv;
            }
        }
    }
}

// ---------------- Kernel 3: deformed gather + weighted combine --------------
// 4 points per block, 64 lanes per point, 4 channels per lane (float4).
__global__ __launch_bounds__(256) void gather_kernel(
    const float* __restrict__ feat_t, const float* __restrict__ params,
    float* __restrict__ out)
{
    int t = threadIdx.x;
    int p = t >> 6;
    int lane = t & 63;
    int pt = blockIdx.x * 4 + p;
    int b = pt >> 13;
    const float* pp = params + (size_t)pt * 10;
    const float* fb = feat_t + (size_t)b * LIN * C_DIM;
    int c = lane * 4;
    float ax = 0.0f, ay = 0.0f, az = 0.0f, aw = 0.0f;
#pragma unroll
    for (int k = 0; k < KK; k++) {
        float ix = pp[k];
        float w  = pp[5 + k];
        float x0 = floorf(ix);
        int i0 = (int)x0;
        int i1 = min(i0 + 1, LIN - 1);
        float fr = ix - x0;
        float4 f0 = *(const float4*)(fb + (size_t)i0 * C_DIM + c);
        float4 f1 = *(const float4*)(fb + (size_t)i1 * C_DIM + c);
        float w0 = w * (1.0f - fr), w1 = w * fr;
        ax = fmaf(w0, f0.x, fmaf(w1, f1.x, ax));
        ay = fmaf(w0, f0.y, fmaf(w1, f1.y, ay));
        az = fmaf(w0, f0.z, fmaf(w1, f1.z, az));
        aw = fmaf(w0, f0.w, fmaf(w1, f1.w, aw));
    }
    float4 res = make_float4(ax, ay, az, aw);
    *(float4*)(out + (size_t)pt * C_DIM + c) = res;
}

extern "C" void kernel_launch(void* const* d_in, const int* in_sizes, int n_in,
                              void* d_out, int out_size, void* d_ws, size_t ws_size,
                              hipStream_t stream) {
    const float* feat   = (const float*)d_in[0];
    const float* coords = (const float*)d_in[1];
    const float* cell   = (const float*)d_in[2];
    const float* W1 = (const float*)d_in[3];
    const float* b1 = (const float*)d_in[4];
    const float* Wr = (const float*)d_in[5];
    const float* br = (const float*)d_in[6];
    const float* W3 = (const float*)d_in[7];
    const float* b3 = (const float*)d_in[8];
    float* out = (float*)d_out;

    float* feat_t = (float*)d_ws;                              // B*LIN*C floats
    float* params = feat_t + (size_t)B_DIM * LIN * C_DIM;      // B*N*10 floats

    dim3 tb(32, 8);
    dim3 tg(LIN / 32, C_DIM / 32, B_DIM);
    transpose_kernel<<<tg, tb, 0, stream>>>(feat, feat_t);

    int nPts = B_DIM * N_PTS;
    mlp_kernel<<<nPts / 64, 256, 0, stream>>>(feat_t, coords, cell,
                                              W1, b1, Wr, br, W3, b3, params);

    gather_kernel<<<nPts / 4, 256, 0, stream>>>(feat_t, params, out);
}

// Round 2
// 163.462 us; speedup vs baseline: 1.2550x; 1.2550x over previous
//
#include <hip/hip_runtime.h>
#include <hip/hip_bf16.h>
#include <math.h>

#define KK 5
#define C_DIM 256
#define LIN 4096
#define B_DIM 4
#define N_PTS 8192
#define PTS 32          // points per MLP block

__device__ __forceinline__ float leaky(float v) { return v >= 0.0f ? v : 0.2f * v; }
__device__ __forceinline__ float softplus_f(float v) { return v > 20.0f ? v : log1pf(expf(v)); }
__device__ __forceinline__ float bflo(unsigned u) { return __uint_as_float(u << 16); }
__device__ __forceinline__ float bfhi(unsigned u) { return __uint_as_float(u & 0xFFFF0000u); }

// ---------------- Kernel 1: transpose feat [B][C][L] -> bf16 feat_t [B][L][C]
__global__ __launch_bounds__(256) void transpose_kernel(
    const float* __restrict__ feat, __hip_bfloat16* __restrict__ feat_t)
{
    __shared__ float tile[32][33];
    int b  = blockIdx.z;
    int l0 = blockIdx.x * 32;
    int c0 = blockIdx.y * 32;
    const float* src = feat + (size_t)b * C_DIM * LIN;
    __hip_bfloat16* dst = feat_t + (size_t)b * LIN * C_DIM;
    int tx = threadIdx.x, ty = threadIdx.y;   // (32, 8)
#pragma unroll
    for (int i = 0; i < 4; i++)
        tile[ty + i * 8][tx] = src[(size_t)(c0 + ty + i * 8) * LIN + (l0 + tx)];
    __syncthreads();
#pragma unroll
    for (int i = 0; i < 4; i++)
        dst[(size_t)(l0 + ty + i * 8) * C_DIM + (c0 + tx)] =
            __float2bfloat16(tile[tx][ty + i * 8]);
}

// ---------------- Kernel 2: per-point MLP -> params (5 ix + 5 norm weights) -
// 32 points/block, 256 threads, weights streamed from global (L1/L2-resident).
__global__ __launch_bounds__(256) void mlp_kernel(
    const __hip_bfloat16* __restrict__ feat_t,
    const float* __restrict__ coords,
    const float* __restrict__ cell,
    const float* __restrict__ W1, const float* __restrict__ b1,
    const float* __restrict__ Wr, const float* __restrict__ br,
    const float* __restrict__ W3, const float* __restrict__ b3,
    float* __restrict__ params)
{
    __shared__ float anch[PTS][260];   // 33280 B, rows 0,2,4,6 -> banks 0,8,16,24
    __shared__ float h1s[PTS][68];     //  8704 B
    __shared__ float h2s[PTS][68];     //  8704 B
    __shared__ float outs[PTS][12];    //  1536 B
    __shared__ float xs[PTS], cls[PTS];

    const int t = threadIdx.x;
    const int base = blockIdx.x * PTS;
    const int bb = base >> 13;                       // 8192 pts per batch
    const ushort* fb = (const ushort*)feat_t + (size_t)bb * LIN * C_DIM;

    // --- gather anchors: 8 threads/point, 64 channels each (bf16 -> f32 lerp)
    {
        int p = t >> 3, l8 = t & 7;
        int pt = base + p;
        float x = coords[pt];
        float ix = fminf(fmaxf((x + 1.0f) * 0.5f * (float)(LIN - 1), 0.0f), (float)(LIN - 1));
        float x0 = floorf(ix);
        int i0 = min((int)x0, LIN - 1);
        int i1 = min(i0 + 1, LIN - 1);
        float fr = ix - x0, om = 1.0f - fr;
        if (l8 == 0) { xs[p] = x; cls[p] = cell[pt]; }
        const ushort* r0 = fb + (size_t)i0 * C_DIM;
        const ushort* r1 = fb + (size_t)i1 * C_DIM;
#pragma unroll
        for (int q = 0; q < 4; q++) {
            int c = l8 * 8 + q * 64;
            uint4 u0 = *(const uint4*)(r0 + c);
            uint4 u1 = *(const uint4*)(r1 + c);
            float4 lo, hi;
            lo.x = bflo(u0.x) * om + bflo(u1.x) * fr;
            lo.y = bfhi(u0.x) * om + bfhi(u1.x) * fr;
            lo.z = bflo(u0.y) * om + bflo(u1.y) * fr;
            lo.w = bfhi(u0.y) * om + bfhi(u1.y) * fr;
            hi.x = bflo(u0.z) * om + bflo(u1.z) * fr;
            hi.y = bfhi(u0.z) * om + bfhi(u1.z) * fr;
            hi.z = bflo(u0.w) * om + bflo(u1.w) * fr;
            hi.w = bfhi(u0.w) * om + bfhi(u1.w) * fr;
            *(float4*)&anch[p][c]     = lo;
            *(float4*)&anch[p][c + 4] = hi;
        }
    }
    __syncthreads();

    const int j0 = (t & 15) * 4;        // output columns j0..j0+3
    const int p0 = (t >> 4) * 2;        // points p0, p0+1

    // --- layer 1: [32 x 258] @ [258 x 64], 2pts x 4j per thread ------------
    {
        float4 bv = *(const float4*)(b1 + j0);
        float4 acc0 = bv, acc1 = bv;
#pragma unroll 4
        for (int c = 0; c < 256; c += 4) {
            float4 a0 = *(const float4*)&anch[p0][c];
            float4 a1 = *(const float4*)&anch[p0 + 1][c];
            float4 w0 = *(const float4*)(W1 + (size_t)(c + 0) * 64 + j0);
            float4 w1 = *(const float4*)(W1 + (size_t)(c + 1) * 64 + j0);
            float4 w2 = *(const float4*)(W1 + (size_t)(c + 2) * 64 + j0);
            float4 w3 = *(const float4*)(W1 + (size_t)(c + 3) * 64 + j0);
            acc0.x = fmaf(a0.x, w0.x, acc0.x); acc0.y = fmaf(a0.x, w0.y, acc0.y);
            acc0.z = fmaf(a0.x, w0.z, acc0.z); acc0.w = fmaf(a0.x, w0.w, acc0.w);
            acc0.x = fmaf(a0.y, w1.x, acc0.x); acc0.y = fmaf(a0.y, w1.y, acc0.y);
            acc0.z = fmaf(a0.y, w1.z, acc0.z); acc0.w = fmaf(a0.y, w1.w, acc0.w);
            acc0.x = fmaf(a0.z, w2.x, acc0.x); acc0.y = fmaf(a0.z, w2.y, acc0.y);
            acc0.z = fmaf(a0.z, w2.z, acc0.z); acc0.w = fmaf(a0.z, w2.w, acc0.w);
            acc0.x = fmaf(a0.w, w3.x, acc0.x); acc0.y = fmaf(a0.w, w3.y, acc0.y);
            acc0.z = fmaf(a0.w, w3.z, acc0.z); acc0.w = fmaf(a0.w, w3.w, acc0.w);
            acc1.x = fmaf(a1.x, w0.x, acc1.x); acc1.y = fmaf(a1.x, w0.y, acc1.y);
            acc1.z = fmaf(a1.x, w0.z, acc1.z); acc1.w = fmaf(a1.x, w0.w, acc1.w);
            acc1.x = fmaf(a1.y, w1.x, acc1.x); acc1.y = fmaf(a1.y, w1.y, acc1.y);
            acc1.z = fmaf(a1.y, w1.z, acc1.z); acc1.w = fmaf(a1.y, w1.w, acc1.w);
            acc1.x = fmaf(a1.z, w2.x, acc1.x); acc1.y = fmaf(a1.z, w2.y, acc1.y);
            acc1.z = fmaf(a1.z, w2.z, acc1.z); acc1.w = fmaf(a1.z, w2.w, acc1.w);
            acc1.x = fmaf(a1.w, w3.x, acc1.x); acc1.y = fmaf(a1.w, w3.y, acc1.y);
            acc1.z = fmaf(a1.w, w3.z, acc1.z); acc1.w = fmaf(a1.w, w3.w, acc1.w);
        }
        float4 wx = *(const float4*)(W1 + (size_t)256 * 64 + j0);
        float4 wc = *(const float4*)(W1 + (size_t)257 * 64 + j0);
        float x0v = xs[p0], c0v = cls[p0], x1v = xs[p0 + 1], c1v = cls[p0 + 1];
        acc0.x = fmaf(x0v, wx.x, fmaf(c0v, wc.x, acc0.x));
        acc0.y = fmaf(x0v, wx.y, fmaf(c0v, wc.y, acc0.y));
        acc0.z = fmaf(x0v, wx.z, fmaf(c0v, wc.z, acc0.z));
        acc0.w = fmaf(x0v, wx.w, fmaf(c0v, wc.w, acc0.w));
        acc1.x = fmaf(x1v, wx.x, fmaf(c1v, wc.x, acc1.x));
        acc1.y = fmaf(x1v, wx.y, fmaf(c1v, wc.y, acc1.y));
        acc1.z = fmaf(x1v, wx.z, fmaf(c1v, wc.z, acc1.z));
        acc1.w = fmaf(x1v, wx.w, fmaf(c1v, wc.w, acc1.w));
        float4 o0 = make_float4(leaky(acc0.x), leaky(acc0.y), leaky(acc0.z), leaky(acc0.w));
        float4 o1 = make_float4(leaky(acc1.x), leaky(acc1.y), leaky(acc1.z), leaky(acc1.w));
        *(float4*)&h1s[p0][j0]     = o0;
        *(float4*)&h1s[p0 + 1][j0] = o1;
    }
    __syncthreads();

    // --- layer 2 (residual) -------------------------------------------------
    {
        float4 bv = *(const float4*)(br + j0);
        float4 acc0 = bv, acc1 = bv;
#pragma unroll 4
        for (int l = 0; l < 64; l++) {
            float h0 = h1s[p0][l];
            float h1 = h1s[p0 + 1][l];
            float4 w = *(const float4*)(Wr + (size_t)l * 64 + j0);
            acc0.x = fmaf(h0, w.x, acc0.x); acc0.y = fmaf(h0, w.y, acc0.y);
            acc0.z = fmaf(h0, w.z, acc0.z); acc0.w = fmaf(h0, w.w, acc0.w);
            acc1.x = fmaf(h1, w.x, acc1.x); acc1.y = fmaf(h1, w.y, acc1.y);
            acc1.z = fmaf(h1, w.z, acc1.z); acc1.w = fmaf(h1, w.w, acc1.w);
        }
        float4 hp0 = *(const float4*)&h1s[p0][j0];
        float4 hp1 = *(const float4*)&h1s[p0 + 1][j0];
        float4 o0 = make_float4(leaky(hp0.x + acc0.x), leaky(hp0.y + acc0.y),
                                leaky(hp0.z + acc0.z), leaky(hp0.w + acc0.w));
        float4 o1 = make_float4(leaky(hp1.x + acc1.x), leaky(hp1.y + acc1.y),
                                leaky(hp1.z + acc1.z), leaky(hp1.w + acc1.w));
        *(float4*)&h2s[p0][j0]     = o0;
        *(float4*)&h2s[p0 + 1][j0] = o1;
    }
    __syncthreads();

    // --- layer 3: 12 outputs ------------------------------------------------
    {
        int p = t & 31;
        int o = t >> 5;                 // 0..7
        for (int oo = o; oo < 12; oo += 8) {
            float acc = b3[oo];
#pragma unroll 4
            for (int l = 0; l < 64; l++)
                acc = fmaf(h2s[p][l], W3[(size_t)l * 12 + oo], acc);
            outs[p][oo] = acc;
        }
    }
    __syncthreads();

    // --- epilogue: sample coords + normalized weights -----------------------
    if (t < PTS) {
        int pt = base + t;
        float x = xs[t];
        float r = softplus_f(outs[t][0]) + 0.3f;
        r = fminf(fmaxf(r, 0.3f), 2.0f);
        float sg = softplus_f(outs[t][1]) + 0.5f;
        sg = fminf(fmaxf(sg, 0.5f), 3.0f);
        float denom = (sg * 2.0f) * (sg * 2.0f) + 1e-8f;
        const float BASEv[KK] = {-2.0f, -1.0f, 0.0f, 1.0f, 2.0f};
        float ixk[KK], wk[KK];
        float wsum = 0.0f;
#pragma unroll
        for (int k = 0; k < KK; k++) {
            float res = tanhf(outs[t][2 + k]) * 0.5f;
            float off = r * BASEv[k] + res;
            float dx = x + off * (2.0f / (float)(LIN - 1));
            float ix = (dx + 1.0f) * 0.5f * (float)(LIN - 1);
            ix = fminf(fmaxf(ix, 0.0f), (float)(LIN - 1));
            float gate = outs[t][2 + KK + k];
            float wgeo = expf(-0.5f * off * off / denom);
            float sig = 1.0f / (1.0f + expf(-gate));
            float w = wgeo * sig;
            ixk[k] = ix; wk[k] = w; wsum += w;
        }
        float inv = 1.0f / (wsum + 1e-8f);
        float* pp = params + (size_t)pt * 10;
#pragma unroll
        for (int k = 0; k < KK; k++) {
            pp[k]     = ixk[k];
            pp[5 + k] = wk[k] * inv;
        }
    }
}

// ---------------- Kernel 3: deformed gather + weighted combine (bf16 feat) --
// 8 points/block, 32 lanes/point, 8 channels/lane.
__global__ __launch_bounds__(256) void gather_kernel(
    const __hip_bfloat16* __restrict__ feat_t, const float* __restrict__ params,
    float* __restrict__ out)
{
    int t = threadIdx.x;
    int p = t >> 5;
    int lane = t & 31;
    int pt = blockIdx.x * 8 + p;
    int b = pt >> 13;
    const float* pp = params + (size_t)pt * 10;
    const ushort* fb = (const ushort*)feat_t + (size_t)b * LIN * C_DIM;
    int c = lane * 8;
    float a0 = 0, a1 = 0, a2 = 0, a3 = 0, a4 = 0, a5 = 0, a6 = 0, a7 = 0;
#pragma unroll
    for (int k = 0; k < KK; k++) {
        float ix = pp[k];
        float w  = pp[5 + k];
        float x0 = floorf(ix);
        int i0 = (int)x0;
        int i1 = min(i0 + 1, LIN - 1);
        float fr = ix - x0;
        uint4 u0 = *(const uint4*)(fb + (size_t)i0 * C_DIM + c);
        uint4 u1 = *(const uint4*)(fb + (size_t)i1 * C_DIM + c);
        float w0 = w * (1.0f - fr), w1 = w * fr;
        a0 = fmaf(w0, bflo(u0.x), fmaf(w1, bflo(u1.x), a0));
        a1 = fmaf(w0, bfhi(u0.x), fmaf(w1, bfhi(u1.x), a1));
        a2 = fmaf(w0, bflo(u0.y), fmaf(w1, bflo(u1.y), a2));
        a3 = fmaf(w0, bfhi(u0.y), fmaf(w1, bfhi(u1.y), a3));
        a4 = fmaf(w0, bflo(u0.z), fmaf(w1, bflo(u1.z), a4));
        a5 = fmaf(w0, bfhi(u0.z), fmaf(w1, bfhi(u1.z), a5));
        a6 = fmaf(w0, bflo(u0.w), fmaf(w1, bflo(u1.w), a6));
        a7 = fmaf(w0, bfhi(u0.w), fmaf(w1, bfhi(u1.w), a7));
    }
    float* op = out + (size_t)pt * C_DIM + c;
    *(float4*)op       = make_float4(a0, a1, a2, a3);
    *(float4*)(op + 4) = make_float4(a4, a5, a6, a7);
}

extern "C" void kernel_launch(void* const* d_in, const int* in_sizes, int n_in,
                              void* d_out, int out_size, void* d_ws, size_t ws_size,
                              hipStream_t stream) {
    const float* feat   = (const float*)d_in[0];
    const float* coords = (const float*)d_in[1];
    const float* cell   = (const float*)d_in[2];
    const float* W1 = (const float*)d_in[3];
    const float* b1 = (const float*)d_in[4];
    const float* Wr = (const float*)d_in[5];
    const float* br = (const float*)d_in[6];
    const float* W3 = (const float*)d_in[7];
    const float* b3 = (const float*)d_in[8];
    float* out = (float*)d_out;

    __hip_bfloat16* feat_t = (__hip_bfloat16*)d_ws;                 // B*LIN*C bf16
    float* params = (float*)((char*)d_ws + (size_t)B_DIM * LIN * C_DIM * 2);

    dim3 tb(32, 8);
    dim3 tg(LIN / 32, C_DIM / 32, B_DIM);
    transpose_kernel<<<tg, tb, 0, stream>>>(feat, feat_t);

    int nPts = B_DIM * N_PTS;
    mlp_kernel<<<nPts / PTS, 256, 0, stream>>>(feat_t, coords, cell,
                                               W1, b1, Wr, br, W3, b3, params);

    gather_kernel<<<nPts / 8, 256, 0, stream>>>(feat_t, params, out);
}

// Round 3
// 128.700 us; speedup vs baseline: 1.5940x; 1.2701x over previous
//
#include <hip/hip_runtime.h>
#include <math.h>

#define KK 5
#define C_DIM 256
#define LIN 4096
#define B_DIM 4
#define N_PTS 8192
#define PTS 32          // points per MLP block

typedef short short8 __attribute__((ext_vector_type(8)));
typedef float f32x4  __attribute__((ext_vector_type(4)));

__device__ __forceinline__ float leaky(float v) { return v >= 0.0f ? v : 0.2f * v; }
__device__ __forceinline__ float softplus_f(float v) { return v > 20.0f ? v : log1pf(expf(v)); }
__device__ __forceinline__ float bflo(unsigned u) { return __uint_as_float(u << 16); }
__device__ __forceinline__ float bfhi(unsigned u) { return __uint_as_float(u & 0xFFFF0000u); }
__device__ __forceinline__ ushort f2bf(float f) {           // RNE f32 -> bf16 bits
    unsigned u = __float_as_uint(f);
    u += 0x7FFFu + ((u >> 16) & 1u);
    return (ushort)(u >> 16);
}
__device__ __forceinline__ float bf2f(ushort h) { return __uint_as_float((unsigned)h << 16); }

// ---------------- Kernel 0: transpose + hi/lo-split weights (one-off) -------
// W1 [258][64] f32 -> W1t_{hi,lo} [64][264] bf16 (k>=256 zero; x/cell rows on VALU)
// Wr [64][64]  f32 -> Wrt_{hi,lo} [64][72]  bf16
__global__ __launch_bounds__(256) void prep_weights(
    const float* __restrict__ W1, const float* __restrict__ Wr,
    ushort* __restrict__ W1t_hi, ushort* __restrict__ W1t_lo,
    ushort* __restrict__ Wrt_hi, ushort* __restrict__ Wrt_lo)
{
    int i = blockIdx.x * 256 + threadIdx.x;
    if (i < 64 * 264) {
        int j = i / 264, k = i % 264;
        float v = (k < 256) ? W1[(size_t)k * 64 + j] : 0.0f;
        ushort hi = f2bf(v);
        W1t_hi[i] = hi;
        W1t_lo[i] = f2bf(v - bf2f(hi));
    } else {
        int i2 = i - 64 * 264;
        if (i2 < 64 * 72) {
            int j = i2 / 72, k = i2 % 72;
            float v = (k < 64) ? Wr[(size_t)k * 64 + j] : 0.0f;
            ushort hi = f2bf(v);
            Wrt_hi[i2] = hi;
            Wrt_lo[i2] = f2bf(v - bf2f(hi));
        }
    }
}

// ---------------- Kernel 1: transpose feat [B][C][L] -> bf16 feat_t [B][L][C]
__global__ __launch_bounds__(256) void transpose_kernel(
    const float* __restrict__ feat, ushort* __restrict__ feat_t)
{
    __shared__ float tile[32][33];
    int b  = blockIdx.z;
    int l0 = blockIdx.x * 32;
    int c0 = blockIdx.y * 32;
    const float* src = feat + (size_t)b * C_DIM * LIN;
    ushort* dst = feat_t + (size_t)b * LIN * C_DIM;
    int tx = threadIdx.x, ty = threadIdx.y;   // (32, 8)
#pragma unroll
    for (int i = 0; i < 4; i++)
        tile[ty + i * 8][tx] = src[(size_t)(c0 + ty + i * 8) * LIN + (l0 + tx)];
    __syncthreads();
#pragma unroll
    for (int i = 0; i < 4; i++)
        dst[(size_t)(l0 + ty + i * 8) * C_DIM + (c0 + tx)] = f2bf(tile[tx][ty + i * 8]);
}

// ---------------- Kernel 2: MFMA MLP -> params (5 ix + 5 norm weights) ------
// 32 points/block, 4 waves; wave w owns output cols [16w,16w+16), both M-tiles.
// hi/lo bf16 3-MFMA emulation for near-f32 precision.
__global__ __launch_bounds__(256) void mlp_kernel(
    const ushort* __restrict__ feat_t,
    const float* __restrict__ coords,
    const float* __restrict__ cell,
    const float* __restrict__ W1, const float* __restrict__ b1,
    const float* __restrict__ br,
    const float* __restrict__ W3, const float* __restrict__ b3,
    const ushort* __restrict__ W1t_hi, const ushort* __restrict__ W1t_lo,
    const ushort* __restrict__ Wrt_hi, const ushort* __restrict__ Wrt_lo,
    float* __restrict__ params)
{
    __shared__ ushort Ah[PTS][264], Al[PTS][264];   // anchors hi/lo (33.8 KB)
    __shared__ ushort H1h[PTS][72], H1l[PTS][72];   // h1 hi/lo (9.2 KB)
    __shared__ float  H2[PTS][68];                  // h2 f32 (8.7 KB)
    __shared__ float  outs[PTS][12];
    __shared__ float  xs[PTS], cls[PTS];

    const int t = threadIdx.x;
    const int base = blockIdx.x * PTS;
    const int bb = base >> 13;
    const ushort* fb = feat_t + (size_t)bb * LIN * C_DIM;

    // --- anchor gather: 8 threads/point, 32 channels each, f32 lerp -> hi/lo
    {
        int p = t >> 3, l8 = t & 7;
        int pt = base + p;
        float x = coords[pt];
        float ix = fminf(fmaxf((x + 1.0f) * 0.5f * (float)(LIN - 1), 0.0f), (float)(LIN - 1));
        float x0 = floorf(ix);
        int i0 = min((int)x0, LIN - 1);
        int i1 = min(i0 + 1, LIN - 1);
        float fr = ix - x0, om = 1.0f - fr;
        if (l8 == 0) { xs[p] = x; cls[p] = cell[pt]; }
        const ushort* r0 = fb + (size_t)i0 * C_DIM;
        const ushort* r1 = fb + (size_t)i1 * C_DIM;
#pragma unroll
        for (int q = 0; q < 4; q++) {
            int c = l8 * 8 + q * 64;
            uint4 u0 = *(const uint4*)(r0 + c);
            uint4 u1 = *(const uint4*)(r1 + c);
            float v[8];
            v[0] = bflo(u0.x) * om + bflo(u1.x) * fr;
            v[1] = bfhi(u0.x) * om + bfhi(u1.x) * fr;
            v[2] = bflo(u0.y) * om + bflo(u1.y) * fr;
            v[3] = bfhi(u0.y) * om + bfhi(u1.y) * fr;
            v[4] = bflo(u0.z) * om + bflo(u1.z) * fr;
            v[5] = bfhi(u0.z) * om + bfhi(u1.z) * fr;
            v[6] = bflo(u0.w) * om + bflo(u1.w) * fr;
            v[7] = bfhi(u0.w) * om + bfhi(u1.w) * fr;
            ushort hv[8], lv[8];
#pragma unroll
            for (int e = 0; e < 8; e++) {
                hv[e] = f2bf(v[e]);
                lv[e] = f2bf(v[e] - bf2f(hv[e]));
            }
            *(uint4*)&Ah[p][c] = *(uint4*)hv;
            *(uint4*)&Al[p][c] = *(uint4*)lv;
        }
    }
    __syncthreads();

    const int wave = t >> 6, lane = t & 63;
    const int cr = lane & 15;       // A-frag row / B-frag col / C-frag col
    const int kb = lane >> 4;       // k sub-chunk
    const int jcol = wave * 16 + cr;

    // --- layer 1: [32 x 256] @ [256 x 64] via 3-MFMA hi/lo ------------------
    f32x4 acc0 = {0.f, 0.f, 0.f, 0.f}, acc1 = acc0;
    {
        const ushort* B1h = W1t_hi + (size_t)jcol * 264;
        const ushort* B1l = W1t_lo + (size_t)jcol * 264;
#pragma unroll
        for (int k0 = 0; k0 < 256; k0 += 32) {
            int ko = k0 + kb * 8;
            short8 a0h = *(const short8*)&Ah[cr][ko];
            short8 a0l = *(const short8*)&Al[cr][ko];
            short8 a1h = *(const short8*)&Ah[16 + cr][ko];
            short8 a1l = *(const short8*)&Al[16 + cr][ko];
            short8 bh = *(const short8*)(B1h + ko);
            short8 bl = *(const short8*)(B1l + ko);
            acc0 = __builtin_amdgcn_mfma_f32_16x16x32_bf16(a0h, bh, acc0, 0, 0, 0);
            acc0 = __builtin_amdgcn_mfma_f32_16x16x32_bf16(a0h, bl, acc0, 0, 0, 0);
            acc0 = __builtin_amdgcn_mfma_f32_16x16x32_bf16(a0l, bh, acc0, 0, 0, 0);
            acc1 = __builtin_amdgcn_mfma_f32_16x16x32_bf16(a1h, bh, acc1, 0, 0, 0);
            acc1 = __builtin_amdgcn_mfma_f32_16x16x32_bf16(a1h, bl, acc1, 0, 0, 0);
            acc1 = __builtin_amdgcn_mfma_f32_16x16x32_bf16(a1l, bh, acc1, 0, 0, 0);
        }
    }
    // remainder channels (x, cell) + bias in f32, leaky, stash h1
    float h1a[4], h1b[4];
    {
        float wx = W1[(size_t)256 * 64 + jcol];
        float wc = W1[(size_t)257 * 64 + jcol];
        float bb1 = b1[jcol];
#pragma unroll
        for (int r = 0; r < 4; r++) {
            int p0 = kb * 4 + r;
            float v0 = leaky(acc0[r] + xs[p0] * wx + cls[p0] * wc + bb1);
            h1a[r] = v0;
            ushort hi0 = f2bf(v0);
            H1h[p0][jcol] = hi0;
            H1l[p0][jcol] = f2bf(v0 - bf2f(hi0));
            int p1 = 16 + p0;
            float v1 = leaky(acc1[r] + xs[p1] * wx + cls[p1] * wc + bb1);
            h1b[r] = v1;
            ushort hi1 = f2bf(v1);
            H1h[p1][jcol] = hi1;
            H1l[p1][jcol] = f2bf(v1 - bf2f(hi1));
        }
    }
    __syncthreads();

    // --- layer 2 (residual): [32 x 64] @ [64 x 64] --------------------------
    f32x4 r0 = {0.f, 0.f, 0.f, 0.f}, r1 = r0;
    {
        const ushort* B2h = Wrt_hi + (size_t)jcol * 72;
        const ushort* B2l = Wrt_lo + (size_t)jcol * 72;
#pragma unroll
        for (int k0 = 0; k0 < 64; k0 += 32) {
            int ko = k0 + kb * 8;
            short8 a0h = *(const short8*)&H1h[cr][ko];
            short8 a0l = *(const short8*)&H1l[cr][ko];
            short8 a1h = *(const short8*)&H1h[16 + cr][ko];
            short8 a1l = *(const short8*)&H1l[16 + cr][ko];
            short8 bh = *(const short8*)(B2h + ko);
            short8 bl = *(const short8*)(B2l + ko);
            r0 = __builtin_amdgcn_mfma_f32_16x16x32_bf16(a0h, bh, r0, 0, 0, 0);
            r0 = __builtin_amdgcn_mfma_f32_16x16x32_bf16(a0h, bl, r0, 0, 0, 0);
            r0 = __builtin_amdgcn_mfma_f32_16x16x32_bf16(a0l, bh, r0, 0, 0, 0);
            r1 = __builtin_amdgcn_mfma_f32_16x16x32_bf16(a1h, bh, r1, 0, 0, 0);
            r1 = __builtin_amdgcn_mfma_f32_16x16x32_bf16(a1h, bl, r1, 0, 0, 0);
            r1 = __builtin_amdgcn_mfma_f32_16x16x32_bf16(a1l, bh, r1, 0, 0, 0);
        }
        float brv = br[jcol];
#pragma unroll
        for (int r = 0; r < 4; r++) {
            int p0 = kb * 4 + r;
            H2[p0][jcol]      = leaky(h1a[r] + r0[r] + brv);
            H2[16 + p0][jcol] = leaky(h1b[r] + r1[r] + brv);
        }
    }
    __syncthreads();

    // --- layer 3: 12 outputs, f32 VALU --------------------------------------
    {
        int p = t & 31;
        int o = t >> 5;                 // 0..7
        for (int oo = o; oo < 12; oo += 8) {
            float acc = b3[oo];
#pragma unroll 4
            for (int l = 0; l < 64; l++)
                acc = fmaf(H2[p][l], W3[(size_t)l * 12 + oo], acc);
            outs[p][oo] = acc;
        }
    }
    __syncthreads();

    // --- epilogue: sample coords + normalized weights -----------------------
    if (t < PTS) {
        int pt = base + t;
        float x = xs[t];
        float r = softplus_f(outs[t][0]) + 0.3f;
        r = fminf(fmaxf(r, 0.3f), 2.0f);
        float sg = softplus_f(outs[t][1]) + 0.5f;
        sg = fminf(fmaxf(sg, 0.5f), 3.0f);
        float denom = (sg * 2.0f) * (sg * 2.0f) + 1e-8f;
        const float BASEv[KK] = {-2.0f, -1.0f, 0.0f, 1.0f, 2.0f};
        float ixk[KK], wk[KK];
        float wsum = 0.0f;
#pragma unroll
        for (int k = 0; k < KK; k++) {
            float res = tanhf(outs[t][2 + k]) * 0.5f;
            float off = r * BASEv[k] + res;
            float dx = x + off * (2.0f / (float)(LIN - 1));
            float ix = (dx + 1.0f) * 0.5f * (float)(LIN - 1);
            ix = fminf(fmaxf(ix, 0.0f), (float)(LIN - 1));
            float gate = outs[t][2 + KK + k];
            float wgeo = expf(-0.5f * off * off / denom);
            float sig = 1.0f / (1.0f + expf(-gate));
            float w = wgeo * sig;
            ixk[k] = ix; wk[k] = w; wsum += w;
        }
        float inv = 1.0f / (wsum + 1e-8f);
        float* pp = params + (size_t)pt * 10;
#pragma unroll
        for (int k = 0; k < KK; k++) {
            pp[k]     = ixk[k];
            pp[5 + k] = wk[k] * inv;
        }
    }
}

// ---------------- Kernel 3: deformed gather + weighted combine (bf16 feat) --
__global__ __launch_bounds__(256) void gather_kernel(
    const ushort* __restrict__ feat_t, const float* __restrict__ params,
    float* __restrict__ out)
{
    int t = threadIdx.x;
    int p = t >> 5;
    int lane = t & 31;
    int pt = blockIdx.x * 8 + p;
    int b = pt >> 13;
    const float* pp = params + (size_t)pt * 10;
    const ushort* fb = feat_t + (size_t)b * LIN * C_DIM;
    int c = lane * 8;
    float a0 = 0, a1 = 0, a2 = 0, a3 = 0, a4 = 0, a5 = 0, a6 = 0, a7 = 0;
#pragma unroll
    for (int k = 0; k < KK; k++) {
        float ix = pp[k];
        float w  = pp[5 + k];
        float x0 = floorf(ix);
        int i0 = (int)x0;
        int i1 = min(i0 + 1, LIN - 1);
        float fr = ix - x0;
        uint4 u0 = *(const uint4*)(fb + (size_t)i0 * C_DIM + c);
        uint4 u1 = *(const uint4*)(fb + (size_t)i1 * C_DIM + c);
        float w0 = w * (1.0f - fr), w1 = w * fr;
        a0 = fmaf(w0, bflo(u0.x), fmaf(w1, bflo(u1.x), a0));
        a1 = fmaf(w0, bfhi(u0.x), fmaf(w1, bfhi(u1.x), a1));
        a2 = fmaf(w0, bflo(u0.y), fmaf(w1, bflo(u1.y), a2));
        a3 = fmaf(w0, bfhi(u0.y), fmaf(w1, bfhi(u1.y), a3));
        a4 = fmaf(w0, bflo(u0.z), fmaf(w1, bflo(u1.z), a4));
        a5 = fmaf(w0, bfhi(u0.z), fmaf(w1, bfhi(u1.z), a5));
        a6 = fmaf(w0, bflo(u0.w), fmaf(w1, bflo(u1.w), a6));
        a7 = fmaf(w0, bfhi(u0.w), fmaf(w1, bfhi(u1.w), a7));
    }
    float* op = out + (size_t)pt * C_DIM + c;
    *(float4*)op       = make_float4(a0, a1, a2, a3);
    *(float4*)(op + 4) = make_float4(a4, a5, a6, a7);
}

extern "C" void kernel_launch(void* const* d_in, const int* in_sizes, int n_in,
                              void* d_out, int out_size, void* d_ws, size_t ws_size,
                              hipStream_t stream) {
    const float* feat   = (const float*)d_in[0];
    const float* coords = (const float*)d_in[1];
    const float* cell   = (const float*)d_in[2];
    const float* W1 = (const float*)d_in[3];
    const float* b1 = (const float*)d_in[4];
    const float* Wr = (const float*)d_in[5];
    const float* br = (const float*)d_in[6];
    const float* W3 = (const float*)d_in[7];
    const float* b3 = (const float*)d_in[8];
    float* out = (float*)d_out;

    char* ws = (char*)d_ws;
    ushort* feat_t = (ushort*)ws;                       // B*LIN*C bf16 = 33.55 MB
    ws += (size_t)B_DIM * LIN * C_DIM * 2;
    float* params = (float*)ws;                         // 32768*10*4 = 1.31 MB
    ws += (size_t)B_DIM * N_PTS * 10 * 4;
    ushort* W1t_hi = (ushort*)ws; ws += 64 * 264 * 2;
    ushort* W1t_lo = (ushort*)ws; ws += 64 * 264 * 2;
    ushort* Wrt_hi = (ushort*)ws; ws += 64 * 72 * 2;
    ushort* Wrt_lo = (ushort*)ws; ws += 64 * 72 * 2;

    prep_weights<<<(64 * 264 + 64 * 72 + 255) / 256, 256, 0, stream>>>(
        W1, Wr, W1t_hi, W1t_lo, Wrt_hi, Wrt_lo);

    dim3 tb(32, 8);
    dim3 tg(LIN / 32, C_DIM / 32, B_DIM);
    transpose_kernel<<<tg, tb, 0, stream>>>(feat, feat_t);

    int nPts = B_DIM * N_PTS;
    mlp_kernel<<<nPts / PTS, 256, 0, stream>>>(feat_t, coords, cell,
                                               W1, b1, br, W3, b3,
                                               W1t_hi, W1t_lo, Wrt_hi, Wrt_lo,
                                               params);

    gather_kernel<<<nPts / 8, 256, 0, stream>>>(feat_t, params, out);
}